// Round 2
// baseline (9195.395 us; speedup 1.0000x reference)
//
#include <hip/hip_runtime.h>

// LSTM B=64, S=512, D=H=1024 on MI355X (gfx950).
// R5: RMW-free slot barrier + arrival-driven h staging.
// 2 independent recurrence groups (32 batches) x 64 j-slices = 128 blocks
// x 1024 threads. Full K=2048 weights in VGPRs (16 waves = 4 K-quarters x
// 4 row-groups, 64 VGPRs each).
// Sync redesign vs R4 (which was latency-bound on a contended RMW counter):
//   - 1024 sub-slots (group x 64 blocks x 8 epilogue waves), 4B plain sc1
//     epoch stores. NO fetch_add anywhere.
//   - producer wave signals right after s_waitcnt vmcnt(0) drains its OWN
//     h-ring stores -- before the out store, before the block barrier.
//   - each h-wave owns 8 producers: polls their 64 sub-slots with ONE
//     64-lane sc1 load + ballot per iteration; stages each producer's 1KB
//     h-slice the moment it is ready (overlaps straggler wait).
// Per step: P1 {x-waves: x MFMAs | h-waves: poll+stage} B1 {h MFMAs} B2
// {epilogue: reduce/gates/h-store/vmcnt/slot-signal/out-store} B3.

typedef short short8 __attribute__((ext_vector_type(8)));
typedef float float4v __attribute__((ext_vector_type(4)));
typedef unsigned long long u64;

__device__ __forceinline__ short f2bf(float f) {
  union { float f; unsigned u; } v; v.f = f;
  unsigned r = (v.u + 0x7fffu + ((v.u >> 16) & 1u)) >> 16;  // RNE
  return (short)r;
}

__device__ __forceinline__ float sigm(float z) {
  float e = __expf(-fabsf(z));
  float p = 1.0f / (1.0f + e);
  return z >= 0.0f ? p : 1.0f - p;
}

__device__ __forceinline__ float tanh_s(float z) {
  float e = __expf(-2.0f * fabsf(z));
  float r = (1.0f - e) / (1.0f + e);
  return z >= 0.0f ? r : -r;
}

// one-time x fp32 [b][s][d] -> bf16 [s][b][d]
__global__ __launch_bounds__(256) void xconv(const float* __restrict__ x,
                                             short* __restrict__ xbf) {
  const int gid = blockIdx.x * 256 + threadIdx.x;
  const long i8 = (long)gid * 8;
  const int d  = (int)(i8 & 1023);
  const int bs = (int)(i8 >> 10);
  const int s  = bs & 511;
  const int b  = bs >> 9;
  const float4v* src = (const float4v*)(x + i8);
  float4v v0 = src[0], v1 = src[1];
  short8 o;
  o[0]=f2bf(v0[0]); o[1]=f2bf(v0[1]); o[2]=f2bf(v0[2]); o[3]=f2bf(v0[3]);
  o[4]=f2bf(v1[0]); o[5]=f2bf(v1[1]); o[6]=f2bf(v1[2]); o[7]=f2bf(v1[3]);
  *(short8*)(xbf + (((size_t)(s * 64 + b)) << 10) + d) = o;
}

template <bool XBF>
__global__ __launch_bounds__(1024, 4) void lstm_persist(
    const float* __restrict__ x, const short* __restrict__ xbf,
    const float* __restrict__ Wx, const float* __restrict__ bx,
    const float* __restrict__ Wh, const float* __restrict__ bh,
    float* __restrict__ out, unsigned* slots, short* hbuf)
{
  __shared__ short hS[32 * 1024];      // 64 KB staged h, XOR-swizzled rows of 2 KB
  __shared__ float red[4][32][68];     // 34.8 KB [kq][batch][n], +4 pad

  const int tid  = threadIdx.x;
  const int bid  = blockIdx.x;
  const int g    = bid & 1;        // batch group
  const int js   = bid >> 1;       // j-slice 0..63
  const int lane = tid & 63;
  const int w    = tid >> 6;       // wave 0..15
  const int kq   = w >> 2;         // K-quarter: 0,1 -> x, 2,3 -> h
  const int rg   = w & 3;          // row-group (16 rows each)
  const int l15  = lane & 15;
  const int lh   = lane >> 4;

  unsigned* slot_g = slots + g * 512;             // 2 KB per-group slot array
  short* hb_g = hbuf + (size_t)g * 65536;         // 2 x 32 x 1024 bf16 ring

  // ---- static weights: 16 rows per wave, n = l15 = jj*4+gi ----
  short8 bw[16];
  {
    const int gi  = l15 & 3;
    const int jj  = l15 >> 2;
    const int row = gi * 1024 + js * 16 + rg * 4 + jj;
    const float* Wsrc = (kq < 2) ? (Wx + (size_t)row * 1024 + kq * 512)
                                 : (Wh + (size_t)row * 1024 + (kq - 2) * 512);
    #pragma unroll
    for (int ks = 0; ks < 16; ++ks) {
      const float* p = Wsrc + ks * 32 + lh * 8;
      float4v v0 = *(const float4v*)p;
      float4v v1 = *(const float4v*)(p + 4);
      short8 o;
      o[0]=f2bf(v0[0]); o[1]=f2bf(v0[1]); o[2]=f2bf(v0[2]); o[3]=f2bf(v0[3]);
      o[4]=f2bf(v1[0]); o[5]=f2bf(v1[1]); o[6]=f2bf(v1[2]); o[7]=f2bf(v1[3]);
      bw[ks] = o;
    }
  }

  // ---- epilogue identity: tid<512 owns (batch eb, hidden ejj) ----
  const int eb  = tid >> 4;        // 0..31 (block-local batch)
  const int ejj = tid & 15;        // 0..15 (block-local j)
  const int jg  = js * 16 + ejj;   // global j
  float bias[4] = {0.f, 0.f, 0.f, 0.f};
  if (tid < 512) {
    #pragma unroll
    for (int gi = 0; gi < 4; ++gi) bias[gi] = bx[gi * 1024 + jg] + bh[gi * 1024 + jg];
  }
  float c_reg = 0.0f, h_keep = 0.0f;

  // ---- h-wave staging identity (w >= 8): owns 8 producer j-slices ----
  const int pbase = (w - 8) * 8;   // producer base
  const int srow  = lane >> 1;     // 0..31 staged row
  const int shalf = lane & 1;      // which 16B of the 32B row-chunk

  char* const hSB = (char*)hS;

  for (int t = 0; t < 512; ++t) {
    float4v acc[2];
    acc[0] = (float4v){0.f, 0.f, 0.f, 0.f};
    acc[1] = (float4v){0.f, 0.f, 0.f, 0.f};

    if (kq < 2) {
      // ---- P1 (x-waves): x MFMAs, no h dependency ----
      if (XBF) {
        const short* xb = xbf + ((size_t)t << 16) + kq * 512 + lh * 8;
        #pragma unroll
        for (int ks = 0; ks < 16; ++ks) {
          #pragma unroll
          for (int mt = 0; mt < 2; ++mt) {
            const int b = g * 32 + mt * 16 + l15;
            short8 a = *(const short8*)(xb + ((size_t)b << 10) + ks * 32);
            acc[mt] = __builtin_amdgcn_mfma_f32_16x16x32_bf16(a, bw[ks], acc[mt], 0, 0, 0);
          }
        }
      } else {
        const float* Ab = x + (size_t)t * 1024 + kq * 512 + lh * 8;
        #pragma unroll
        for (int ks = 0; ks < 16; ++ks) {
          #pragma unroll
          for (int mt = 0; mt < 2; ++mt) {
            const int b = g * 32 + mt * 16 + l15;
            const float* p = Ab + (size_t)b * 524288 + ks * 32;
            float4v v0 = *(const float4v*)p;
            float4v v1 = *(const float4v*)(p + 4);
            short8 a;
            a[0]=f2bf(v0[0]); a[1]=f2bf(v0[1]); a[2]=f2bf(v0[2]); a[3]=f2bf(v0[3]);
            a[4]=f2bf(v1[0]); a[5]=f2bf(v1[1]); a[6]=f2bf(v1[2]); a[7]=f2bf(v1[3]);
            acc[mt] = __builtin_amdgcn_mfma_f32_16x16x32_bf16(a, bw[ks], acc[mt], 0, 0, 0);
          }
        }
      }
      #pragma unroll
      for (int mt = 0; mt < 2; ++mt)
        #pragma unroll
        for (int r = 0; r < 4; ++r)
          red[kq][mt * 16 + lh * 4 + r][rg * 16 + l15] = acc[mt][r];
    } else {
      // ---- P1 (h-waves): poll 64 sub-slots, stage slices as they arrive ----
      const unsigned target = (unsigned)t;
      const short* hb = hb_g + (size_t)(t & 1) * 32768;
      const unsigned* sp = slot_g + (pbase << 3) + lane;  // 64 contiguous sub-slots
      unsigned got = 0;
      while (got != 0xFFu) {
        const unsigned v = __hip_atomic_load(sp, __ATOMIC_RELAXED, __HIP_MEMORY_SCOPE_AGENT);
        const unsigned long long rdy = __ballot(v >= target);
        #pragma unroll
        for (int p = 0; p < 8; ++p) {
          if (!(got & (1u << p)) && (((rdy >> (p * 8)) & 0xFFull) == 0xFFull)) {
            const int jp = pbase + p;
            const u64* q = (const u64*)(hb + srow * 1024 + jp * 16 + shalf * 8);
            union { u64 u[2]; short8 s; } uu;
            uu.u[0] = __hip_atomic_load(q,     __ATOMIC_RELAXED, __HIP_MEMORY_SCOPE_AGENT);
            uu.u[1] = __hip_atomic_load(q + 1, __ATOMIC_RELAXED, __HIP_MEMORY_SCOPE_AGENT);
            unsigned byte = ((unsigned)srow << 11) + (unsigned)(jp * 32 + shalf * 16);
            byte ^= ((unsigned)(srow & 7) << 4);
            *(short8*)(hSB + byte) = uu.s;
            got |= 1u << p;
          }
        }
        if (got != 0xFFu) __builtin_amdgcn_s_sleep(1);
      }
    }
    __syncthreads();   // B1: h staged (x partials already in red)

    if (kq >= 2) {
      // ---- P2 (h-waves): swizzled ds_read_b128 frags + MFMA ----
      const unsigned cb = (unsigned)((kq - 2) * 1024 + lh * 16);
      const unsigned xr = (unsigned)((l15 & 7) << 4);
      #pragma unroll
      for (int ks = 0; ks < 16; ++ks) {
        #pragma unroll
        for (int mt = 0; mt < 2; ++mt) {
          const unsigned byte = (((unsigned)(mt * 16 + l15) << 11) + cb + ks * 64) ^ xr;
          short8 a = *(const short8*)(hSB + byte);
          acc[mt] = __builtin_amdgcn_mfma_f32_16x16x32_bf16(a, bw[ks], acc[mt], 0, 0, 0);
        }
      }
      #pragma unroll
      for (int mt = 0; mt < 2; ++mt)
        #pragma unroll
        for (int r = 0; r < 4; ++r)
          red[kq][mt * 16 + lh * 4 + r][rg * 16 + l15] = acc[mt][r];
    }
    __syncthreads();   // B2: all partials in red

    if (tid < 512) {
      // ---- P3: K-reduce + gates + state + signal + stores ----
      const int base = (ejj >> 2) * 16 + (ejj & 3) * 4;
      const float4v r0 = *(const float4v*)&red[0][eb][base];
      const float4v r1 = *(const float4v*)&red[1][eb][base];
      const float4v r2 = *(const float4v*)&red[2][eb][base];
      const float4v r3 = *(const float4v*)&red[3][eb][base];
      const float s0 = r0[0] + r1[0] + r2[0] + r3[0] + bias[0];
      const float s1 = r0[1] + r1[1] + r2[1] + r3[1] + bias[1];
      const float s2 = r0[2] + r1[2] + r2[2] + r3[2] + bias[2];
      const float s3 = r0[3] + r1[3] + r2[3] + r3[3] + bias[3];
      const float ig = sigm(s0);
      const float fg = sigm(s1);
      const float og = sigm(s2);
      const float gg = tanh_s(s3);
      c_reg = fg * c_reg + ig * gg;
      const float hh = og * tanh_s(c_reg);
      h_keep = hh;
      // h-ring store FIRST (pack 2 bf16 via shfl -> one u32 sc1 store)
      unsigned hv = (unsigned)(unsigned short)f2bf(hh);
      unsigned nb = (unsigned)__shfl_xor((int)hv, 1, 64);
      if ((ejj & 1) == 0) {
        unsigned vv = hv | (nb << 16);
        unsigned* dst = (unsigned*)(hb_g + (size_t)((t + 1) & 1) * 32768 + eb * 1024 + jg);
        __hip_atomic_store(dst, vv, __ATOMIC_RELAXED, __HIP_MEMORY_SCOPE_AGENT);
      }
      // drain OWN h stores, then publish this wave's sub-slot epoch
      asm volatile("s_waitcnt vmcnt(0)" ::: "memory");
      if (lane == 0)
        __hip_atomic_store(slot_g + js * 8 + w, (unsigned)(t + 1),
                           __ATOMIC_RELAXED, __HIP_MEMORY_SCOPE_AGENT);
      // out store AFTER the signal -- its HBM ack is off the cross-block chain
      out[((size_t)(g * 32 + eb) * 512 + t) * 1024 + jg] = hh;
    }
    __syncthreads();   // B3: red safe to overwrite next step
  }

  if (tid < 512) {
    const size_t BSH = (size_t)64 * 512 * 1024;
    out[BSH + (size_t)(g * 32 + eb) * 1024 + jg] = h_keep;
    out[BSH + 65536 + (size_t)(g * 32 + eb) * 1024 + jg] = c_reg;
  }
}

extern "C" void kernel_launch(void* const* d_in, const int* in_sizes, int n_in,
                              void* d_out, int out_size, void* d_ws, size_t ws_size,
                              hipStream_t stream) {
  (void)in_sizes; (void)n_in; (void)out_size;
  const float* x  = (const float*)d_in[0];
  const float* Wx = (const float*)d_in[1];
  const float* bx = (const float*)d_in[2];
  const float* Wh = (const float*)d_in[3];
  const float* bh = (const float*)d_in[4];
  float* out = (float*)d_out;

  unsigned* slots = (unsigned*)d_ws;                        // 8 KB sub-slot epochs
  short* hbuf     = (short*)((char*)d_ws + 8192);           // 2 groups x 2 x 64 KB h ring
  short* xbf      = (short*)((char*)d_ws + 8192 + 262144);  // 64 MB bf16 x [t][b][d]
  const size_t need_xbf = 8192u + 262144u + (size_t)64 * 512 * 1024 * 2;

  hipMemsetAsync(d_ws, 0, 8192 + 262144, stream);           // slots + h0 = 0

  if (ws_size >= need_xbf) {
    hipLaunchKernelGGL(xconv, dim3(16384), dim3(256), 0, stream, x, xbf);
    hipLaunchKernelGGL(lstm_persist<true>, dim3(128), dim3(1024), 0, stream,
                       x, xbf, Wx, bx, Wh, bh, out, slots, hbuf);
  } else {
    hipLaunchKernelGGL(lstm_persist<false>, dim3(128), dim3(1024), 0, stream,
                       x, hbuf, Wx, bx, Wh, bh, out, slots, hbuf);
  }
}

// Round 3
// 7822.367 us; speedup vs baseline: 1.1755x; 1.1755x over previous
//
#include <hip/hip_runtime.h>

// LSTM B=64, S=512, D=H=1024 on MI355X (gfx950).
// R6: RMW-free per-block slot barrier + R4 bulk pipelined staging.
// 2 recurrence groups (32 batches) x 64 j-slices = 128 blocks x 1024 thr.
// Full K=2048 weights in VGPRs (16 waves = 4 K-quarters x 4 row-groups).
// Cross-block chain per step (everything else overlaps):
//   epi: gates -> ring store -> vmcnt(0) [ring only] -> LDS arrive++
//   wave15: spin LDS arrive==8 -> plain sc1 slot store (own 64B line)
//   consumers: 8 h-waves each poll 64 slots (1 load + ballot) -> bulk
//              pipelined stage (8 loads in flight) -> B1 -> h MFMA.
// out stores are fire-and-forget (drain at next B1, off the chain).
// No fetch_add anywhere; 2 barriers/step (B1, B2).

typedef short short8 __attribute__((ext_vector_type(8)));
typedef float float4v __attribute__((ext_vector_type(4)));
typedef unsigned long long u64;

__device__ __forceinline__ short f2bf(float f) {
  union { float f; unsigned u; } v; v.f = f;
  unsigned r = (v.u + 0x7fffu + ((v.u >> 16) & 1u)) >> 16;  // RNE
  return (short)r;
}

__device__ __forceinline__ float sigm(float z) {
  float e = __expf(-fabsf(z));
  float p = 1.0f / (1.0f + e);
  return z >= 0.0f ? p : 1.0f - p;
}

__device__ __forceinline__ float tanh_s(float z) {
  float e = __expf(-2.0f * fabsf(z));
  float r = (1.0f - e) / (1.0f + e);
  return z >= 0.0f ? r : -r;
}

// one-time x fp32 [b][s][d] -> bf16 [s][b][d]
__global__ __launch_bounds__(256) void xconv(const float* __restrict__ x,
                                             short* __restrict__ xbf) {
  const int gid = blockIdx.x * 256 + threadIdx.x;
  const long i8 = (long)gid * 8;
  const int d  = (int)(i8 & 1023);
  const int bs = (int)(i8 >> 10);
  const int s  = bs & 511;
  const int b  = bs >> 9;
  const float4v* src = (const float4v*)(x + i8);
  float4v v0 = src[0], v1 = src[1];
  short8 o;
  o[0]=f2bf(v0[0]); o[1]=f2bf(v0[1]); o[2]=f2bf(v0[2]); o[3]=f2bf(v0[3]);
  o[4]=f2bf(v1[0]); o[5]=f2bf(v1[1]); o[6]=f2bf(v1[2]); o[7]=f2bf(v1[3]);
  *(short8*)(xbf + (((size_t)(s * 64 + b)) << 10) + d) = o;
}

template <bool XBF>
__global__ __launch_bounds__(1024, 4) void lstm_persist(
    const float* __restrict__ x, const short* __restrict__ xbf,
    const float* __restrict__ Wx, const float* __restrict__ bx,
    const float* __restrict__ Wh, const float* __restrict__ bh,
    float* __restrict__ out, unsigned* slots, short* hbuf)
{
  __shared__ short hS[32 * 1024];      // 64 KB staged h, XOR-swizzled rows of 2 KB
  __shared__ float red[4][32][68];     // 34.8 KB [kq][batch][n], +4 pad
  __shared__ unsigned arrive;          // epi-wave arrival counter (monotonic)

  const int tid  = threadIdx.x;
  const int bid  = blockIdx.x;
  const int g    = bid & 1;        // batch group
  const int js   = bid >> 1;       // j-slice 0..63
  const int lane = tid & 63;
  const int w    = tid >> 6;       // wave 0..15
  const int kq   = w >> 2;         // K-quarter: 0,1 -> x, 2,3 -> h
  const int rg   = w & 3;          // row-group (16 rows each)
  const int l15  = lane & 15;
  const int lh   = lane >> 4;

  unsigned* slot_g = slots + g * 1024;            // 64 slots x 64B line each
  short* hb_g = hbuf + (size_t)g * 65536;         // 2 x 32 x 1024 bf16 ring

  // ---- static weights: 16 rows per wave, n = l15 = jj*4+gi ----
  short8 bw[16];
  {
    const int gi  = l15 & 3;
    const int jj  = l15 >> 2;
    const int row = gi * 1024 + js * 16 + rg * 4 + jj;
    const float* Wsrc = (kq < 2) ? (Wx + (size_t)row * 1024 + kq * 512)
                                 : (Wh + (size_t)row * 1024 + (kq - 2) * 512);
    #pragma unroll
    for (int ks = 0; ks < 16; ++ks) {
      const float* p = Wsrc + ks * 32 + lh * 8;
      float4v v0 = *(const float4v*)p;
      float4v v1 = *(const float4v*)(p + 4);
      short8 o;
      o[0]=f2bf(v0[0]); o[1]=f2bf(v0[1]); o[2]=f2bf(v0[2]); o[3]=f2bf(v0[3]);
      o[4]=f2bf(v1[0]); o[5]=f2bf(v1[1]); o[6]=f2bf(v1[2]); o[7]=f2bf(v1[3]);
      bw[ks] = o;
    }
  }

  // ---- epilogue identity: tid<512 owns (batch eb, hidden ejj) ----
  const int eb  = tid >> 4;        // 0..31 (block-local batch)
  const int ejj = tid & 15;        // 0..15 (block-local j)
  const int jg  = js * 16 + ejj;   // global j
  float bias[4] = {0.f, 0.f, 0.f, 0.f};
  if (tid < 512) {
    #pragma unroll
    for (int gi = 0; gi < 4; ++gi) bias[gi] = bx[gi * 1024 + jg] + bh[gi * 1024 + jg];
  }
  float c_reg = 0.0f, h_keep = 0.0f;

  if (tid == 0)
    __hip_atomic_store(&arrive, 0u, __ATOMIC_RELAXED, __HIP_MEMORY_SCOPE_WORKGROUP);
  __syncthreads();

  char* const hSB = (char*)hS;

  for (int t = 0; t < 512; ++t) {
    float4v acc[2];
    acc[0] = (float4v){0.f, 0.f, 0.f, 0.f};
    acc[1] = (float4v){0.f, 0.f, 0.f, 0.f};

    if (kq < 2) {
      // ---- P1 (x-waves): x MFMAs, no h dependency ----
      if (XBF) {
        const short* xb = xbf + ((size_t)t << 16) + kq * 512 + lh * 8;
        #pragma unroll
        for (int ks = 0; ks < 16; ++ks) {
          #pragma unroll
          for (int mt = 0; mt < 2; ++mt) {
            const int b = g * 32 + mt * 16 + l15;
            short8 a = *(const short8*)(xb + ((size_t)b << 10) + ks * 32);
            acc[mt] = __builtin_amdgcn_mfma_f32_16x16x32_bf16(a, bw[ks], acc[mt], 0, 0, 0);
          }
        }
      } else {
        const float* Ab = x + (size_t)t * 1024 + kq * 512 + lh * 8;
        #pragma unroll
        for (int ks = 0; ks < 16; ++ks) {
          #pragma unroll
          for (int mt = 0; mt < 2; ++mt) {
            const int b = g * 32 + mt * 16 + l15;
            const float* p = Ab + (size_t)b * 524288 + ks * 32;
            float4v v0 = *(const float4v*)p;
            float4v v1 = *(const float4v*)(p + 4);
            short8 a;
            a[0]=f2bf(v0[0]); a[1]=f2bf(v0[1]); a[2]=f2bf(v0[2]); a[3]=f2bf(v0[3]);
            a[4]=f2bf(v1[0]); a[5]=f2bf(v1[1]); a[6]=f2bf(v1[2]); a[7]=f2bf(v1[3]);
            acc[mt] = __builtin_amdgcn_mfma_f32_16x16x32_bf16(a, bw[ks], acc[mt], 0, 0, 0);
          }
        }
      }
      #pragma unroll
      for (int mt = 0; mt < 2; ++mt)
        #pragma unroll
        for (int r = 0; r < 4; ++r)
          red[kq][mt * 16 + lh * 4 + r][rg * 16 + l15] = acc[mt][r];
    } else {
      // ---- P1 (h-waves): wait-all via slot ballot, then BULK stage ----
      const unsigned target = (unsigned)t;
      {
        const unsigned* sp = slot_g + (size_t)lane * 16;   // one slot per 64B line
        for (;;) {
          const unsigned v = __hip_atomic_load(sp, __ATOMIC_RELAXED, __HIP_MEMORY_SCOPE_AGENT);
          if (__ballot(v >= target) == ~0ull) break;
          __builtin_amdgcn_s_sleep(1);
        }
      }
      // bulk stage 64 KB with 512 threads: 8 pipelined 16B loads each
      const int tau = tid - 512;
      const int row = tau >> 4;          // 0..31
      const int sec = tau & 15;          // 0..15
      const short* src = hb_g + (size_t)(t & 1) * 32768 + row * 1024 + sec * 8;
      #pragma unroll
      for (int i = 0; i < 8; ++i) {
        const u64* p = (const u64*)(src + i * 128);
        union { u64 q[2]; short8 s; } u;
        u.q[0] = __hip_atomic_load(p,     __ATOMIC_RELAXED, __HIP_MEMORY_SCOPE_AGENT);
        u.q[1] = __hip_atomic_load(p + 1, __ATOMIC_RELAXED, __HIP_MEMORY_SCOPE_AGENT);
        const unsigned byte = (((unsigned)row << 11) + sec * 16 + i * 256)
                              ^ ((unsigned)(row & 7) << 4);
        *(short8*)(hSB + byte) = u.s;
      }
    }
    __syncthreads();   // B1: h staged (x partials already in red); drains out stores

    if (kq >= 2) {
      // ---- P2 (h-waves): swizzled ds_read_b128 frags + MFMA ----
      const unsigned cb = (unsigned)((kq - 2) * 1024 + lh * 16);
      const unsigned xr = (unsigned)((l15 & 7) << 4);
      #pragma unroll
      for (int ks = 0; ks < 16; ++ks) {
        #pragma unroll
        for (int mt = 0; mt < 2; ++mt) {
          const unsigned byte = (((unsigned)(mt * 16 + l15) << 11) + cb + ks * 64) ^ xr;
          short8 a = *(const short8*)(hSB + byte);
          acc[mt] = __builtin_amdgcn_mfma_f32_16x16x32_bf16(a, bw[ks], acc[mt], 0, 0, 0);
        }
      }
      #pragma unroll
      for (int mt = 0; mt < 2; ++mt)
        #pragma unroll
        for (int r = 0; r < 4; ++r)
          red[kq][mt * 16 + lh * 4 + r][rg * 16 + l15] = acc[mt][r];
    }
    __syncthreads();   // B2: all partials in red (drains everything)

    if (tid < 512) {
      // ---- P3 (epi waves 0-7): reduce + gates + ring store + arrive ----
      const int base = (ejj >> 2) * 16 + (ejj & 3) * 4;
      const float4v r0 = *(const float4v*)&red[0][eb][base];
      const float4v r1 = *(const float4v*)&red[1][eb][base];
      const float4v r2 = *(const float4v*)&red[2][eb][base];
      const float4v r3 = *(const float4v*)&red[3][eb][base];
      const float s0 = r0[0] + r1[0] + r2[0] + r3[0] + bias[0];
      const float s1 = r0[1] + r1[1] + r2[1] + r3[1] + bias[1];
      const float s2 = r0[2] + r1[2] + r2[2] + r3[2] + bias[2];
      const float s3 = r0[3] + r1[3] + r2[3] + r3[3] + bias[3];
      const float ig = sigm(s0);
      const float fg = sigm(s1);
      const float og = sigm(s2);
      const float gg = tanh_s(s3);
      c_reg = fg * c_reg + ig * gg;
      const float hh = og * tanh_s(c_reg);
      h_keep = hh;
      // ring store (pack 2 bf16 via shfl -> one u32 sc1 store)
      unsigned hv = (unsigned)(unsigned short)f2bf(hh);
      unsigned nb = (unsigned)__shfl_xor((int)hv, 1, 64);
      if ((ejj & 1) == 0) {
        unsigned vv = hv | (nb << 16);
        unsigned* dst = (unsigned*)(hb_g + (size_t)((t + 1) & 1) * 32768 + eb * 1024 + jg);
        __hip_atomic_store(dst, vv, __ATOMIC_RELAXED, __HIP_MEMORY_SCOPE_AGENT);
      }
      // drain the ring store ONLY (B2 already drained everything else),
      // then register this wave's arrival locally (LDS, cheap).
      asm volatile("s_waitcnt vmcnt(0)" ::: "memory");
      if (lane == 0)
        __hip_atomic_fetch_add(&arrive, 1u, __ATOMIC_RELAXED, __HIP_MEMORY_SCOPE_WORKGROUP);
      // out store AFTER the arrival: fire-and-forget, drains at next B1.
      out[((size_t)(g * 32 + eb) * 512 + t) * 1024 + jg] = hh;
    } else if (w == 15) {
      // ---- block signaler: spin on local LDS counter, then slot store ----
      const unsigned tgt = 8u * (unsigned)(t + 1);
      while (__hip_atomic_load(&arrive, __ATOMIC_RELAXED, __HIP_MEMORY_SCOPE_WORKGROUP) < tgt)
        __builtin_amdgcn_s_sleep(1);
      if (lane == 0)
        __hip_atomic_store(slot_g + (size_t)js * 16, (unsigned)(t + 1),
                           __ATOMIC_RELAXED, __HIP_MEMORY_SCOPE_AGENT);
    }
    // no B3: red/hS reuse is ordered by B1/B2 + slot-wait (see header)
  }

  if (tid < 512) {
    const size_t BSH = (size_t)64 * 512 * 1024;
    out[BSH + (size_t)(g * 32 + eb) * 1024 + jg] = h_keep;
    out[BSH + 65536 + (size_t)(g * 32 + eb) * 1024 + jg] = c_reg;
  }
}

extern "C" void kernel_launch(void* const* d_in, const int* in_sizes, int n_in,
                              void* d_out, int out_size, void* d_ws, size_t ws_size,
                              hipStream_t stream) {
  (void)in_sizes; (void)n_in; (void)out_size;
  const float* x  = (const float*)d_in[0];
  const float* Wx = (const float*)d_in[1];
  const float* bx = (const float*)d_in[2];
  const float* Wh = (const float*)d_in[3];
  const float* bh = (const float*)d_in[4];
  float* out = (float*)d_out;

  unsigned* slots = (unsigned*)d_ws;                        // 8 KB: 2 x 64 slots, 64B apart
  short* hbuf     = (short*)((char*)d_ws + 8192);           // 2 groups x 2 x 64 KB h ring
  short* xbf      = (short*)((char*)d_ws + 8192 + 262144);  // 64 MB bf16 x [t][b][d]
  const size_t need_xbf = 8192u + 262144u + (size_t)64 * 512 * 1024 * 2;

  hipMemsetAsync(d_ws, 0, 8192 + 262144, stream);           // slots + h0 = 0

  if (ws_size >= need_xbf) {
    hipLaunchKernelGGL(xconv, dim3(16384), dim3(256), 0, stream, x, xbf);
    hipLaunchKernelGGL(lstm_persist<true>, dim3(128), dim3(1024), 0, stream,
                       x, xbf, Wx, bx, Wh, bh, out, slots, hbuf);
  } else {
    hipLaunchKernelGGL(lstm_persist<false>, dim3(128), dim3(1024), 0, stream,
                       x, hbuf, Wx, bx, Wh, bh, out, slots, hbuf);
  }
}